// Round 1
// baseline (1043.532 us; speedup 1.0000x reference)
//
#include <hip/hip_runtime.h>

// NodeEdgeProjection: out[b, e, f] = in[b, e/127, f]
//   B=256, N=128 nodes, E=128*127=16256 edges, F=64 features, fp32.
// EDGE_RECEIVER[e] == e // 127, so this is a pure broadcast: each 64-float
// node row replicated 127x. Write-bandwidth bound: 1.065 GB out, 8 MB in.
//
// R1: the harness's poison-fill proves 6.2 TB/s streaming writes on this
// buffer; the previous kernel (1 chunk/block, 32768 blocks) ran at ~2.9 TB/s
// because every wave paid one dependent-load latency for only 8 store
// instructions of work. This version gives each block 8 consecutive
// (b,node) chunks: 8 independent loads issued up front, ONE vmcnt(0) wait,
// then 64 back-to-back nontemporal stores per wave.

typedef float vfloat4 __attribute__((ext_vector_type(4)));

#define NNODES   128
#define DEG      127            // edges per receiving node (N-1)
#define FEAT4    16             // 64 floats = 16 vfloat4 per row
#define CHUNK4   (DEG * FEAT4)  // 2032 vfloat4 per (b,node) output chunk
#define BLOCK    256
#define CPB      8              // (b,node) chunks per block

__global__ __launch_bounds__(BLOCK)
void NodeEdgeProjection_5025111736904_kernel(const vfloat4* __restrict__ in,
                                             vfloat4* __restrict__ out) {
    const int t = threadIdx.x;
    const size_t c0 = (size_t)blockIdx.x * CPB;   // first (b*128+node) chunk

    // Each thread's output slots p = t + k*256 all satisfy p % 16 == t % 16,
    // so per chunk it needs exactly one vfloat4 of the source row
    // (16 unique addresses per wave, 4-way lane broadcast, L1/L2-served).
    const vfloat4* __restrict__ src = in + c0 * FEAT4 + (t & (FEAT4 - 1));

    vfloat4 v[CPB];
#pragma unroll
    for (int c = 0; c < CPB; ++c)
        v[c] = src[(size_t)c * FEAT4];            // 8 independent loads in flight

    // Single wait for all source rows; every store below then issues with
    // no further stalls (statically-indexed v[] stays in registers).
    asm volatile("s_waitcnt vmcnt(0)" ::: "memory");

    // Output region for this block is contiguous: CPB * 2032 vfloat4.
    vfloat4* __restrict__ dst = out + c0 * CHUNK4 + t;

#pragma unroll
    for (int c = 0; c < CPB; ++c) {
#pragma unroll
        for (int k = 0; k < 8; ++k) {             // 2032 = 7*256 + 240
            if (t + k * BLOCK < CHUNK4) {
                __builtin_nontemporal_store(v[c], &dst[c * CHUNK4 + k * BLOCK]);
            }
        }
    }
}

extern "C" void kernel_launch(void* const* d_in, const int* in_sizes, int n_in,
                              void* d_out, int out_size, void* d_ws, size_t ws_size,
                              hipStream_t stream) {
    const vfloat4* in  = (const vfloat4*)d_in[0];   // [256,128,64] fp32
    vfloat4*       out = (vfloat4*)d_out;           // [256,16256,64] fp32

    const int grid = 256 * NNODES / CPB;            // 4096 blocks, 8 chunks each
    NodeEdgeProjection_5025111736904_kernel<<<grid, BLOCK, 0, stream>>>(in, out);
}

// Round 2
// 1041.001 us; speedup vs baseline: 1.0024x; 1.0024x over previous
//
#include <hip/hip_runtime.h>

// NodeEdgeProjection: out[b, e, f] = in[b, e/127, f]
//   B=256, N=128 nodes, E=128*127=16256 edges, F=64 features, fp32.
// EDGE_RECEIVER[e] == e // 127, so this is a pure broadcast: each 64-float
// node row replicated 127x. Write-bandwidth bound: 1.065 GB out, 8 MB in.
//
// R2: single-variable test vs R1 — PLAIN stores instead of
// __builtin_nontemporal_store. R1 (CPB=8, one-wait, nt) was byte-identical
// in time to R0 (CPB=1, nt): both ~2.9 TB/s writes, while the harness's
// fillBufferAligned hits 6.25 TB/s on the same buffer with plain stores.
// Theory: gfx950's nt store path forfeits L2 write-combining/writeback
// aggregation (~2x effective HBM cost per line); plain write-allocate
// stores (full-line coverage per wave: 64 lanes x 16 B = 1024 B contiguous)
// match the fill's proven-fast path.

typedef float vfloat4 __attribute__((ext_vector_type(4)));

#define NNODES   128
#define DEG      127            // edges per receiving node (N-1)
#define FEAT4    16             // 64 floats = 16 vfloat4 per row
#define CHUNK4   (DEG * FEAT4)  // 2032 vfloat4 per (b,node) output chunk
#define BLOCK    256
#define CPB      8              // (b,node) chunks per block

__global__ __launch_bounds__(BLOCK)
void NodeEdgeProjection_5025111736904_kernel(const vfloat4* __restrict__ in,
                                             vfloat4* __restrict__ out) {
    const int t = threadIdx.x;
    const size_t c0 = (size_t)blockIdx.x * CPB;   // first (b*128+node) chunk

    // Per chunk each thread needs exactly one vfloat4 of the source row
    // (p = t + k*256 => p % 16 == t % 16): 16 unique addresses per wave,
    // 4-way lane broadcast, L1/L2-served.
    const vfloat4* __restrict__ src = in + c0 * FEAT4 + (t & (FEAT4 - 1));

    vfloat4 v[CPB];
#pragma unroll
    for (int c = 0; c < CPB; ++c)
        v[c] = src[(size_t)c * FEAT4];            // 8 independent loads in flight

    // Output region for this block is contiguous: CPB * 2032 vfloat4.
    vfloat4* __restrict__ dst = out + c0 * CHUNK4 + t;

#pragma unroll
    for (int c = 0; c < CPB; ++c) {
#pragma unroll
        for (int k = 0; k < 8; ++k) {             // 2032 = 7*256 + 240
            if (t + k * BLOCK < CHUNK4) {
                dst[c * CHUNK4 + k * BLOCK] = v[c];   // plain store (no nt)
            }
        }
    }
}

extern "C" void kernel_launch(void* const* d_in, const int* in_sizes, int n_in,
                              void* d_out, int out_size, void* d_ws, size_t ws_size,
                              hipStream_t stream) {
    const vfloat4* in  = (const vfloat4*)d_in[0];   // [256,128,64] fp32
    vfloat4*       out = (vfloat4*)d_out;           // [256,16256,64] fp32

    const int grid = 256 * NNODES / CPB;            // 4096 blocks, 8 chunks each
    NodeEdgeProjection_5025111736904_kernel<<<grid, BLOCK, 0, stream>>>(in, out);
}